// Round 13
// baseline (71158.630 us; speedup 1.0000x reference)
//
#include <hip/hip_runtime.h>
#include <hip/hip_bf16.h>
#include <cstdint>

// LSTM, T=32768 steps, C=512, I=1024 (x 512 | h 512), fp32.
//   1) gx = Wx@x_t + b  -- GEMM over all timesteps (chunked in ws)
//   2) serial recurrence: 64 blocks x 256 threads (R8/R11/R12 structure).
//      R13 changes (both on the serial publish->detect->compute chain):
//      (a) 2-deep PIPELINED poll: two 8-load batches in flight, alternating
//          checks (counted vmcnt via compiler) -> detection quantization
//          ~RTT -> ~RTT/2.   (b) FMA chains split 16 -> 2x8 (shorter dep path).
//      Model: step = publish-flight(1 RTT) + detect(1 RTT) + quantization +
//      compute; (a),(b) attack the last two terms.

#define T_TOTAL 32768
#define NBLK 64

__device__ __forceinline__ float sigm(float x) {
    return 1.0f / (1.0f + __expf(-x));
}
__device__ __forceinline__ float tanh_fast(float x) {
    float ax = fabsf(x);
    float e = __expf(2.0f * ax);          // +inf for large ax is fine -> t = 1
    float t = 1.0f - 2.0f / (e + 1.0f);
    return copysignf(t, x);
}

// ---------------------------------------------------------------------------
// GEMM: for fused c-row jg, gate g: block b = jg>>3, r = jg&7:
//   gx word = (jg>>3)*32 + (jg&7)*4 + g   (block-major, float4 per (b,r))
// ---------------------------------------------------------------------------
__global__ __launch_bounds__(256, 1) void lstm_gemm_x(
    const float* __restrict__ x,
    const float* __restrict__ wf, const float* __restrict__ wi,
    const float* __restrict__ wc, const float* __restrict__ wo,
    const float* __restrict__ bf, const float* __restrict__ bi,
    const float* __restrict__ bc, const float* __restrict__ bo,
    float* __restrict__ gx, int t0, int tend)
{
    __shared__ float xs[16][512];
    const int tid = threadIdx.x;
    const int tt0 = t0 + blockIdx.x * 16;
    const int j0  = blockIdx.y * 128;

    #pragma unroll
    for (int i = 0; i < 8; ++i) {
        int idx  = tid + i * 256;
        int trow = idx >> 7, kq = idx & 127;
        int t    = tt0 + trow;
        float4 v = make_float4(0.f, 0.f, 0.f, 0.f);
        if (t < tend) v = *(const float4*)(x + (size_t)t * 512 + kq * 4);
        *(float4*)&xs[trow][kq * 4] = v;
    }
    __syncthreads();

    const int j  = j0 + (tid & 127);
    const int th = tid >> 7;
    const int g  = j >> 9;
    const int jg = j & 511;
    const float* Wg = (g == 0) ? wf : (g == 1) ? wi : (g == 2) ? wc : wo;
    const float* Bg = (g == 0) ? bf : (g == 1) ? bi : (g == 2) ? bc : bo;
    const float* wrow = Wg + (size_t)jg * 1024;

    float acc[8];
    #pragma unroll
    for (int i = 0; i < 8; ++i) acc[i] = 0.f;

    for (int k = 0; k < 512; k += 4) {
        float4 w4 = *(const float4*)(wrow + k);
        #pragma unroll
        for (int tt = 0; tt < 8; ++tt) {
            float4 x4 = *(const float4*)&xs[th * 8 + tt][k];
            acc[tt] = fmaf(w4.x, x4.x, acc[tt]);
            acc[tt] = fmaf(w4.y, x4.y, acc[tt]);
            acc[tt] = fmaf(w4.z, x4.z, acc[tt]);
            acc[tt] = fmaf(w4.w, x4.w, acc[tt]);
        }
    }

    const float bias = Bg[jg];
    const int   obase = (jg >> 3) * 32 + (jg & 7) * 4 + g;
    #pragma unroll
    for (int tt = 0; tt < 8; ++tt) {
        int t = tt0 + th * 8 + tt;
        if (t < tend) gx[(size_t)(t - t0) * 2048 + obase] = acc[tt] + bias;
    }
}

// ---------------------------------------------------------------------------
// Serial recurrence. 64 blocks x 256 threads (1 block/CU, all co-resident).
// Mailbox: hdq[2][64 blocks][16 u64], block-private 128B lines (R11/R12).
// Publisher: seg==0 relaxed agent atomic STORE of tagged word (R12).
// Reader (R13): wave 0, 2-deep pipelined poll -- batches A,B of 8 loads each
//   alternate; checking A while B is in flight (backend emits vmcnt(8)).
// Weight LDS layout + compute mapping: R8 verbatim (0 conflicts); FMA chains
//   split into dual accumulators per gate (R13b).
// Slot-reuse induction identical to R6-R12 (per-word tags).
// ---------------------------------------------------------------------------
__global__ __launch_bounds__(256, 1) void lstm_serial(
    const float* __restrict__ wf, const float* __restrict__ wi,
    const float* __restrict__ wc, const float* __restrict__ wo,
    const float* __restrict__ gx,
    unsigned long long* __restrict__ hdq,   // [2][64][16] tagged h lines
    float* __restrict__ cstate,
    int t0, int steps, float* __restrict__ out)
{
    __shared__ alignas(16) float4 wlds4[4096];  // [w][g][jj][lane] = 64 KB
    __shared__ alignas(16) float  hl[2][512];   // parity-double-buffered h (4 KB)
    const int b   = blockIdx.x;            // 0..63
    const int tid = threadIdx.x;
    const int r   = tid >> 5;              // 0..7
    const int seg = tid & 31;              // 0..31
    const int w   = tid >> 6;              // wave 0..3
    const int l   = tid & 63;              // lane in wave

    // stage weights once: decode flat index -> (w,g,jj,lane)  [R8 verbatim]
    #pragma unroll
    for (int k = 0; k < 16; ++k) {
        int idx = k * 256 + tid;           // 0..4095
        int ll  = idx & 63;
        int jj  = (idx >> 6) & 3;
        int gg  = (idx >> 8) & 3;
        int ww  = idx >> 10;
        const float* Wp = (gg == 0) ? wf : (gg == 1) ? wi : (gg == 2) ? wc : wo;
        int row = b * 8 + ww * 2 + (ll >> 5);
        wlds4[idx] = *(const float4*)(Wp + (size_t)row * 1024 + 512
                                      + 4 * (ll & 31) + 128 * jj);
    }
    float cold = cstate[b * 8 + r];        // only seg==0's copy is used
    __syncthreads();

    const float4* hl4  = (const float4*)hl;
    const int     wbase = w * 1024 + l;    // + g*256 + jj*64

    for (int s = 0; s < steps; ++s) {
        const int t  = t0 + s;
        const int sp = (t & 1) ^ 1;        // slot holding h_{t-1}
        const int sc = t & 1;              // slot receiving h_t

        // gx prefetch (only consumed by seg==0 lanes)
        float4 gx4 = make_float4(0.f, 0.f, 0.f, 0.f);
        if (seg == 0)
            gx4 = *(const float4*)(gx + (size_t)s * 2048 + b * 32 + r * 4);

        // weight regs: 16 lane-linear b128 reads, issue before the poll
        float4 w00 = wlds4[wbase +   0], w01 = wlds4[wbase +  64];
        float4 w02 = wlds4[wbase + 128], w03 = wlds4[wbase + 192];
        float4 w10 = wlds4[wbase + 256], w11 = wlds4[wbase + 320];
        float4 w12 = wlds4[wbase + 384], w13 = wlds4[wbase + 448];
        float4 w20 = wlds4[wbase + 512], w21 = wlds4[wbase + 576];
        float4 w22 = wlds4[wbase + 640], w23 = wlds4[wbase + 704];
        float4 w30 = wlds4[wbase + 768], w31 = wlds4[wbase + 832];
        float4 w32 = wlds4[wbase + 896], w33 = wlds4[wbase + 960];

        if (tid < 64) {                    // wave 0: 2-deep pipelined poll
            const unsigned need = (unsigned)t;
            const unsigned long long* src =
                hdq + (size_t)sp * 1024 + (tid >> 3) * 16 + (tid & 7);
            unsigned long long A0,A1,A2,A3,A4,A5,A6,A7;
            unsigned long long B0,B1,B2,B3,B4,B5,B6,B7;
#define POLL_LD(X) \
    X##0 = __hip_atomic_load(src,       __ATOMIC_RELAXED, __HIP_MEMORY_SCOPE_AGENT); \
    X##1 = __hip_atomic_load(src + 128, __ATOMIC_RELAXED, __HIP_MEMORY_SCOPE_AGENT); \
    X##2 = __hip_atomic_load(src + 256, __ATOMIC_RELAXED, __HIP_MEMORY_SCOPE_AGENT); \
    X##3 = __hip_atomic_load(src + 384, __ATOMIC_RELAXED, __HIP_MEMORY_SCOPE_AGENT); \
    X##4 = __hip_atomic_load(src + 512, __ATOMIC_RELAXED, __HIP_MEMORY_SCOPE_AGENT); \
    X##5 = __hip_atomic_load(src + 640, __ATOMIC_RELAXED, __HIP_MEMORY_SCOPE_AGENT); \
    X##6 = __hip_atomic_load(src + 768, __ATOMIC_RELAXED, __HIP_MEMORY_SCOPE_AGENT); \
    X##7 = __hip_atomic_load(src + 896, __ATOMIC_RELAXED, __HIP_MEMORY_SCOPE_AGENT)
#define TAGOK(X) (((unsigned)(X##0 >> 32) == need) & ((unsigned)(X##1 >> 32) == need) \
                & ((unsigned)(X##2 >> 32) == need) & ((unsigned)(X##3 >> 32) == need) \
                & ((unsigned)(X##4 >> 32) == need) & ((unsigned)(X##5 >> 32) == need) \
                & ((unsigned)(X##6 >> 32) == need) & ((unsigned)(X##7 >> 32) == need))
            POLL_LD(A);
            int guard = 0;
            for (;;) {
                POLL_LD(B);                       // B in flight while checking A
                if (TAGOK(A) || ++guard >= (1 << 20)) break;
                POLL_LD(A);                       // A in flight while checking B
                if (TAGOK(B) || ++guard >= (1 << 20)) {
                    A0 = B0; A1 = B1; A2 = B2; A3 = B3;
                    A4 = B4; A5 = B5; A6 = B6; A7 = B7;
                    break;
                }
            }
#undef POLL_LD
#undef TAGOK
            hl[sp][tid]       = __uint_as_float((unsigned)A0);
            hl[sp][tid + 64]  = __uint_as_float((unsigned)A1);
            hl[sp][tid + 128] = __uint_as_float((unsigned)A2);
            hl[sp][tid + 192] = __uint_as_float((unsigned)A3);
            hl[sp][tid + 256] = __uint_as_float((unsigned)A4);
            hl[sp][tid + 320] = __uint_as_float((unsigned)A5);
            hl[sp][tid + 384] = __uint_as_float((unsigned)A6);
            hl[sp][tid + 448] = __uint_as_float((unsigned)A7);
        }
        __syncthreads();

        // h: 4 lane-linear b128 reads (r-pairs broadcast)   [R8 verbatim]
        float4 h0 = hl4[sp * 128 + seg];
        float4 h1 = hl4[sp * 128 + seg + 32];
        float4 h2 = hl4[sp * 128 + seg + 64];
        float4 h3 = hl4[sp * 128 + seg + 96];

        // dual accumulators per gate (R13b): dep chain 16 -> 8 + merge
        float a0a = 0.f, a0b = 0.f, a1a = 0.f, a1b = 0.f;
        float a2a = 0.f, a2b = 0.f, a3a = 0.f, a3b = 0.f;
        a0a = fmaf(w00.x, h0.x, a0a); a0a = fmaf(w00.y, h0.y, a0a);
        a0a = fmaf(w00.z, h0.z, a0a); a0a = fmaf(w00.w, h0.w, a0a);
        a0a = fmaf(w01.x, h1.x, a0a); a0a = fmaf(w01.y, h1.y, a0a);
        a0a = fmaf(w01.z, h1.z, a0a); a0a = fmaf(w01.w, h1.w, a0a);
        a0b = fmaf(w02.x, h2.x, a0b); a0b = fmaf(w02.y, h2.y, a0b);
        a0b = fmaf(w02.z, h2.z, a0b); a0b = fmaf(w02.w, h2.w, a0b);
        a0b = fmaf(w03.x, h3.x, a0b); a0b = fmaf(w03.y, h3.y, a0b);
        a0b = fmaf(w03.z, h3.z, a0b); a0b = fmaf(w03.w, h3.w, a0b);

        a1a = fmaf(w10.x, h0.x, a1a); a1a = fmaf(w10.y, h0.y, a1a);
        a1a = fmaf(w10.z, h0.z, a1a); a1a = fmaf(w10.w, h0.w, a1a);
        a1a = fmaf(w11.x, h1.x, a1a); a1a = fmaf(w11.y, h1.y, a1a);
        a1a = fmaf(w11.z, h1.z, a1a); a1a = fmaf(w11.w, h1.w, a1a);
        a1b = fmaf(w12.x, h2.x, a1b); a1b = fmaf(w12.y, h2.y, a1b);
        a1b = fmaf(w12.z, h2.z, a1b); a1b = fmaf(w12.w, h2.w, a1b);
        a1b = fmaf(w13.x, h3.x, a1b); a1b = fmaf(w13.y, h3.y, a1b);
        a1b = fmaf(w13.z, h3.z, a1b); a1b = fmaf(w13.w, h3.w, a1b);

        a2a = fmaf(w20.x, h0.x, a2a); a2a = fmaf(w20.y, h0.y, a2a);
        a2a = fmaf(w20.z, h0.z, a2a); a2a = fmaf(w20.w, h0.w, a2a);
        a2a = fmaf(w21.x, h1.x, a2a); a2a = fmaf(w21.y, h1.y, a2a);
        a2a = fmaf(w21.z, h1.z, a2a); a2a = fmaf(w21.w, h1.w, a2a);
        a2b = fmaf(w22.x, h2.x, a2b); a2b = fmaf(w22.y, h2.y, a2b);
        a2b = fmaf(w22.z, h2.z, a2b); a2b = fmaf(w22.w, h2.w, a2b);
        a2b = fmaf(w23.x, h3.x, a2b); a2b = fmaf(w23.y, h3.y, a2b);
        a2b = fmaf(w23.z, h3.z, a2b); a2b = fmaf(w23.w, h3.w, a2b);

        a3a = fmaf(w30.x, h0.x, a3a); a3a = fmaf(w30.y, h0.y, a3a);
        a3a = fmaf(w30.z, h0.z, a3a); a3a = fmaf(w30.w, h0.w, a3a);
        a3a = fmaf(w31.x, h1.x, a3a); a3a = fmaf(w31.y, h1.y, a3a);
        a3a = fmaf(w31.z, h1.z, a3a); a3a = fmaf(w31.w, h1.w, a3a);
        a3b = fmaf(w32.x, h2.x, a3b); a3b = fmaf(w32.y, h2.y, a3b);
        a3b = fmaf(w32.z, h2.z, a3b); a3b = fmaf(w32.w, h2.w, a3b);
        a3b = fmaf(w33.x, h3.x, a3b); a3b = fmaf(w33.y, h3.y, a3b);
        a3b = fmaf(w33.z, h3.z, a3b); a3b = fmaf(w33.w, h3.w, a3b);

        float a0 = a0a + a0b, a1 = a1a + a1b;
        float a2 = a2a + a2b, a3 = a3a + a3b;

        #pragma unroll
        for (int m = 1; m < 32; m <<= 1) {
            a0 += __shfl_xor(a0, m);
            a1 += __shfl_xor(a1, m);
            a2 += __shfl_xor(a2, m);
            a3 += __shfl_xor(a3, m);
        }

        if (seg == 0) {
            float ff  = sigm(a0 + gx4.x);
            float iiv = sigm(a1 + gx4.y);
            float ccv = tanh_fast(a2 + gx4.z);
            float ov  = sigm(a3 + gx4.w);
            cold = fmaf(ff, cold, iiv * ccv);
            float hnew = tanh_fast(cold) * ov;
            unsigned long long tv = ((unsigned long long)(unsigned)(t + 1) << 32)
                                  | (unsigned long long)__float_as_uint(hnew);
            __hip_atomic_store(hdq + (size_t)sc * 1024 + b * 16 + r, tv,
                               __ATOMIC_RELAXED, __HIP_MEMORY_SCOPE_AGENT);
            if (t == T_TOTAL - 1) {
                out[b * 8 + r]       = cold;
                out[512 + b * 8 + r] = hnew;
            }
        }
    }

    if (seg == 0) cstate[b * 8 + r] = cold;
}

// ---------------------------------------------------------------------------
extern "C" void kernel_launch(void* const* d_in, const int* in_sizes, int n_in,
                              void* d_out, int out_size, void* d_ws, size_t ws_size,
                              hipStream_t stream)
{
    const float* x  = (const float*)d_in[0];
    const float* wf = (const float*)d_in[1];
    const float* bf = (const float*)d_in[2];
    const float* wi = (const float*)d_in[3];
    const float* bi = (const float*)d_in[4];
    const float* wc = (const float*)d_in[5];
    const float* bc = (const float*)d_in[6];
    const float* wo = (const float*)d_in[7];
    const float* bo = (const float*)d_in[8];
    float* out = (float*)d_out;

    char* wsb = (char*)d_ws;
    unsigned long long* hdq = (unsigned long long*)wsb;      // 2*64*16*8 = 16384 B
    float* cst = (float*)(wsb + 16384);                      // 512*4     = 2048 B
    const size_t metaBytes = 16384 + 2048;                   // 18432 (16B aligned)
    float* gxbuf = (float*)(wsb + metaBytes);

    size_t gxCapSteps = (ws_size > metaBytes)
                        ? (ws_size - metaBytes) / (2048 * sizeof(float)) : 0;
    int CH = (gxCapSteps < (size_t)T_TOTAL) ? (int)gxCapSteps : T_TOTAL;
    CH &= ~15;
    if (CH < 16) CH = 16;

    hipMemsetAsync(wsb, 0, metaBytes, stream);   // tags=0 (t=0 poll passes), c=0, h=0

    for (int t0 = 0; t0 < T_TOTAL; t0 += CH) {
        int tend  = t0 + CH; if (tend > T_TOTAL) tend = T_TOTAL;
        int steps = tend - t0;
        dim3 ggrid((steps + 15) / 16, 16);
        lstm_gemm_x<<<ggrid, 256, 0, stream>>>(x, wf, wi, wc, wo,
                                               bf, bi, bc, bo, gxbuf, t0, tend);
        lstm_serial<<<NBLK, 256, 0, stream>>>(wf, wi, wc, wo, gxbuf,
                                              hdq, cst, t0, steps, out);
    }
}